// Round 2
// baseline (22242.122 us; speedup 1.0000x reference)
//
#include <hip/hip_runtime.h>

#define Bv 128
#define Tv 256
#define Dv 512
#define Hv 1024
#define NG 4096   // 4*H

typedef __bf16 bf16x8 __attribute__((ext_vector_type(8)));
typedef float  f32x4  __attribute__((ext_vector_type(4)));
typedef unsigned short u16;
typedef unsigned short ushort8_t __attribute__((ext_vector_type(8)));

__device__ __forceinline__ u16 f2bf(float f){
  unsigned u = __float_as_uint(f);
  u = (u + 0x7FFFu + ((u >> 16) & 1u)) >> 16;
  return (u16)u;
}
__device__ __forceinline__ float bf2f(u16 b){ return __uint_as_float(((unsigned)b) << 16); }
__device__ __forceinline__ float fsig(float x){ return 1.0f / (1.0f + __expf(-x)); }
__device__ __forceinline__ float ftanh(float x){ return 1.0f - 2.0f / (1.0f + __expf(2.0f * x)); }

// ---------------- setup kernels ----------------

__global__ void cvt_f32_bf16(const float* __restrict__ src, u16* __restrict__ dst, int n4){
  int i = blockIdx.x * 256 + threadIdx.x;
  if (i < n4){
    float4 v = ((const float4*)src)[i];
    ushort4 o;
    o.x = f2bf(v.x); o.y = f2bf(v.y); o.z = f2bf(v.z); o.w = f2bf(v.w);
    ((ushort4*)dst)[i] = o;
  }
}

// Pack 4 gate matrices [K, 1024] fp32 into MFMA B-frag layout:
// out index o = ((ntile*KT + ktile)*64 + lane)*8 + j
__global__ void pack_b(const float* __restrict__ Wi, const float* __restrict__ Wf,
                       const float* __restrict__ Wg, const float* __restrict__ Wo,
                       u16* __restrict__ dst, int KTm1, int ntshift){
  int o = blockIdx.x * 256 + threadIdx.x;
  int j = o & 7;
  int lane = (o >> 3) & 63;
  int kt = (o >> 9) & KTm1;
  int ntile = o >> ntshift;
  int k = kt * 32 + ((lane >> 4) << 3) + j;
  int n = ntile * 16 + (lane & 15);
  const float* src = (n < 1024) ? Wi : (n < 2048) ? Wf : (n < 3072) ? Wg : Wo;
  dst[o] = f2bf(src[k * 1024 + (n & 1023)]);
}

__global__ void pack_bias(const float* __restrict__ bi, const float* __restrict__ bfp,
                          const float* __restrict__ bg, const float* __restrict__ bo,
                          float* __restrict__ dst){
  int n = blockIdx.x * 256 + threadIdx.x;   // 0..4095
  const float* s = (n < 1024) ? bi : (n < 2048) ? bfp : (n < 3072) ? bg : bo;
  dst[n] = s[n & 1023];
}

// ---------------- pre-GEMM: Z = A @ Wpacked + bias ----------------
__global__ __launch_bounds__(256) void pregemm(const u16* __restrict__ A,
                                               const u16* __restrict__ Wp,
                                               const float* __restrict__ bias,
                                               u16* __restrict__ Z,
                                               int K){
  int w = threadIdx.x >> 6, lane = threadIdx.x & 63;
  int quad = lane >> 4, l15 = lane & 15;
  int nblk = blockIdx.x;   // 0..63
  int mblk = blockIdx.y;   // 0..255
  int KT = K >> 5;
  const u16* Arow0 = A + (size_t)(mblk * 128 + w * 32 + l15) * K;
  const u16* Arow1 = Arow0 + (size_t)16 * K;
  f32x4 acc[2][4] = {};
  for (int kt = 0; kt < KT; ++kt){
    int kofs = kt * 32 + quad * 8;
    bf16x8 a0 = *(const bf16x8*)(Arow0 + kofs);
    bf16x8 a1 = *(const bf16x8*)(Arow1 + kofs);
#pragma unroll
    for (int g = 0; g < 4; ++g){
      int ntile = nblk * 4 + g;
      bf16x8 b = *(const bf16x8*)(Wp + ((size_t)(ntile * KT + kt) * 64 + lane) * 8);
      acc[0][g] = __builtin_amdgcn_mfma_f32_16x16x32_bf16(a0, b, acc[0][g], 0, 0, 0);
      acc[1][g] = __builtin_amdgcn_mfma_f32_16x16x32_bf16(a1, b, acc[1][g], 0, 0, 0);
    }
  }
#pragma unroll
  for (int mt = 0; mt < 2; ++mt){
    int rowbase = mblk * 128 + w * 32 + mt * 16 + quad * 4;
#pragma unroll
    for (int g = 0; g < 4; ++g){
      int n = (nblk * 4 + g) * 16 + l15;
      float bv = bias[n];
#pragma unroll
      for (int r = 0; r < 4; ++r){
        Z[(size_t)(rowbase + r) * NG + n] = f2bf(acc[mt][g][r] + bv);
      }
    }
  }
}

// ---------------- persistent recurrent scan (one launch per layer) ----------------
// grid 256 blocks x 128 threads. block = (mgrp = bid>>6: rows mgrp*32..+32,
// cgrp = bid&63: h-cols cgrp*16..+16, all 4 gates). wave = 16-row mtile.
// U slice (128 KB, B-frag layout) cached in LDS once. c in VGPRs across steps.
// Per-step sync: generation barrier among the 64 blocks sharing mgrp, with
// agent-scope fences (cross-XCD L2 writeback + invalidate).
__global__ __launch_bounds__(128, 1)
void lstm_scan(const u16* __restrict__ Up, const u16* __restrict__ Z,
               u16* __restrict__ hA, u16* __restrict__ hB,
               u16* __restrict__ dst_bf, float* __restrict__ out_h,
               float* __restrict__ out_c,
               int* __restrict__ bar_arrive, int* __restrict__ bar_gen,
               int last)
{
  extern __shared__ u16 Ulds[];           // 65536 elems = 128 KB
  const int tid  = threadIdx.x;
  const int w    = tid >> 6;              // 0..1
  const int lane = tid & 63;
  const int quad = lane >> 4, l15 = lane & 15;
  const int mgrp = blockIdx.x >> 6;       // 0..3
  const int cgrp = blockIdx.x & 63;       // 0..63

  // stage U slice: 4 contiguous 32KB gate chunks
  {
    const int CH = 16384;
#pragma unroll
    for (int g = 0; g < 4; ++g){
      const ushort8_t* src = (const ushort8_t*)(Up + (size_t)(g * 64 + cgrp) * CH);
      ushort8_t* dst = (ushort8_t*)(Ulds + g * CH);
      for (int i = tid; i < CH / 8; i += 128) dst[i] = src[i];
    }
  }
  __syncthreads();

  const int row0 = mgrp * 32 + w * 16;
  const int arow = row0 + l15;
  const int j    = cgrp * 16 + l15;
  float c[4] = {0.f, 0.f, 0.f, 0.f};
  int* arr = bar_arrive + mgrp;
  int* gen = bar_gen + mgrp;

  for (int t = 0; t < Tv; ++t){
    const u16* hp = (t & 1) ? hB : hA;
    u16*       hn = (t & 1) ? hA : hB;

    const u16* Ar = hp + (size_t)arow * Hv + quad * 8;
    bf16x8 a[32];
#pragma unroll
    for (int kt = 0; kt < 32; ++kt) a[kt] = *(const bf16x8*)(Ar + kt * 32);

    f32x4 acc[4] = {};
#pragma unroll
    for (int kt = 0; kt < 32; ++kt){
#pragma unroll
      for (int g = 0; g < 4; ++g){
        const bf16x8 b = *(const bf16x8*)(Ulds + (((g << 5) + kt) << 9) + (lane << 3));
        acc[g] = __builtin_amdgcn_mfma_f32_16x16x32_bf16(a[kt], b, acc[g], 0, 0, 0);
      }
    }

#pragma unroll
    for (int r = 0; r < 4; ++r){
      const int brow = row0 + quad * 4 + r;
      const u16* zr = Z + ((size_t)brow * Tv + t) * NG;
      float pi = acc[0][r] + bf2f(zr[j]);
      float pf = acc[1][r] + bf2f(zr[Hv + j]);
      float pg = acc[2][r] + bf2f(zr[2 * Hv + j]);
      float po = acc[3][r] + bf2f(zr[3 * Hv + j]);
      float ig = fsig(pi), fg = fsig(pf), gg = ftanh(pg), og = fsig(po);
      float cn = fg * c[r] + ig * gg;
      c[r] = cn;
      float h = og * ftanh(cn);
      hn[(size_t)brow * Hv + j] = f2bf(h);
      if (!last){
        dst_bf[((size_t)brow * Tv + t) * Hv + j] = f2bf(h);
      } else {
        out_h[((size_t)brow * Tv + t) * Hv + j] = h;
        out_c[((size_t)t * Bv + brow) * Hv + j] = cn;
      }
    }

    // ---- inter-block barrier (64 blocks sharing mgrp) ----
    __syncthreads();
    if (tid == 0){
      __threadfence();   // release: drain stores + L2 writeback (agent scope)
      int prev = __hip_atomic_fetch_add(arr, 1, __ATOMIC_RELAXED, __HIP_MEMORY_SCOPE_AGENT);
      if (prev == 63){
        __hip_atomic_store(arr, 0, __ATOMIC_RELAXED, __HIP_MEMORY_SCOPE_AGENT);
        __hip_atomic_fetch_add(gen, 1, __ATOMIC_RELEASE, __HIP_MEMORY_SCOPE_AGENT);
      } else {
        while (__hip_atomic_load(gen, __ATOMIC_RELAXED, __HIP_MEMORY_SCOPE_AGENT) < t + 1){
          __builtin_amdgcn_s_sleep(2);
        }
      }
      __threadfence();   // acquire: L1/L2 invalidate so next h reads are fresh
    }
    __syncthreads();
  }
}

// ---------------- host ----------------

extern "C" void kernel_launch(void* const* d_in, const int* in_sizes, int n_in,
                              void* d_out, int out_size, void* d_ws, size_t ws_size,
                              hipStream_t stream){
  const float* x = (const float*)d_in[0];
  const float *W[3][4], *U[3][4], *bb[3][4];
  for (int l = 0; l < 3; ++l)
    for (int g = 0; g < 4; ++g){
      W[l][g]  = (const float*)d_in[1 + l * 12 + g * 3 + 0];
      U[l][g]  = (const float*)d_in[1 + l * 12 + g * 3 + 1];
      bb[l][g] = (const float*)d_in[1 + l * 12 + g * 3 + 2];
    }

  char* ws = (char*)d_ws;
  u16* Zbf  = (u16*)ws;                                  // 256 MB
  u16* Xb0  = (u16*)(ws + 268435456ull);                 // 64 MB
  u16* Xb1  = (u16*)(ws + 335544320ull);                 // 64 MB
  u16* xbf  = (u16*)(ws + 402653184ull);                 // 32 MB
  u16* Wp[3] = { (u16*)(ws + 436207616ull),
                 (u16*)(ws + 440401920ull),
                 (u16*)(ws + 448790528ull) };
  u16* Up[3] = { (u16*)(ws + 457179136ull),
                 (u16*)(ws + 465567744ull),
                 (u16*)(ws + 473956352ull) };
  float* bias[3] = { (float*)(ws + 482344960ull),
                     (float*)(ws + 482361344ull),
                     (float*)(ws + 482377728ull) };
  int* barv = (int*)(ws + 482394112ull);                 // 24 ints: arrive[12], gen[12]
  u16* hA = (u16*)(ws + 482918400ull);                   // 256 KB
  u16* hB = (u16*)(ws + 483180544ull);                   // 256 KB

  float* out_h = (float*)d_out;
  float* out_c = out_h + (size_t)Bv * Tv * Hv;

  // allow 128 KB dynamic LDS for the scan kernel (idempotent)
  hipFuncSetAttribute((const void*)lstm_scan,
                      hipFuncAttributeMaxDynamicSharedMemorySize, 131072);

  hipMemsetAsync(barv, 0, 24 * sizeof(int), stream);

  cvt_f32_bf16<<<dim3(16384), dim3(256), 0, stream>>>(x, xbf, (Bv * Tv * Dv) / 4);

  for (int l = 0; l < 3; ++l){
    int K = (l == 0) ? Dv : Hv;
    int KT = K >> 5;
    int ntshift = (K == Dv) ? 13 : 14;
    pack_b<<<dim3((NG * K) / 256), dim3(256), 0, stream>>>(
        W[l][0], W[l][1], W[l][2], W[l][3], Wp[l], KT - 1, ntshift);
    pack_b<<<dim3((NG * Hv) / 256), dim3(256), 0, stream>>>(
        U[l][0], U[l][1], U[l][2], U[l][3], Up[l], (Hv >> 5) - 1, 14);
    pack_bias<<<dim3(16), dim3(256), 0, stream>>>(
        bb[l][0], bb[l][1], bb[l][2], bb[l][3], bias[l]);
  }

  const u16* Ain[3] = { xbf, Xb0, Xb1 };
  const int  Kl[3]  = { Dv, Hv, Hv };

  for (int l = 0; l < 3; ++l){
    hipMemsetAsync(hA, 0, (size_t)Bv * Hv * 2, stream);

    pregemm<<<dim3(64, 256), dim3(256), 0, stream>>>(Ain[l], Wp[l], bias[l], Zbf, Kl[l]);

    u16* dst_bf = (l == 0) ? Xb0 : (l == 1) ? Xb1 : nullptr;
    int last = (l == 2) ? 1 : 0;
    lstm_scan<<<dim3(256), dim3(128), 131072, stream>>>(
        Up[l], Zbf, hA, hB, dst_bf, out_h, out_c,
        barv + l * 4, barv + 12 + l * 4, last);
  }
}